// Round 2
// baseline (386.229 us; speedup 1.0000x reference)
//
#include <hip/hip_runtime.h>
#include <stdint.h>

#define N_IMG 8
#define NCLS  80
#define HW    10000
#define PER   (NCLS*HW)      /* 800000 per image */
#define L1B   4096           /* level-1 buckets: score bits 30:19 */
#define L2B   8192           /* level-2 buckets: score bits 18:6  */
#define TOPK  1000
#define CAP   4096
#define KEEP  100
#define PRE_TH 0.05f
#define NMS_TH 0.6f

__device__ __forceinline__ float sigf(float x) {
    return 1.0f / (1.0f + expf(-x));
}

// ---------------- pass 1: level-1 histogram of candidate scores ----------------
__global__ __launch_bounds__(256) void k_hist1(const float* __restrict__ bcls,
                                               const float* __restrict__ bctr,
                                               uint32_t* __restrict__ hist) {
    __shared__ uint32_t h[L1B];
    const int n = blockIdx.y;
    for (int b = threadIdx.x; b < L1B; b += blockDim.x) h[b] = 0;
    __syncthreads();
    const float* cp = bcls + (size_t)n * PER;
    const float* ct = bctr + n * HW;
    const int stride = gridDim.x * blockDim.x;
    for (int i = blockIdx.x * blockDim.x + threadIdx.x; i < PER; i += stride) {
        float cl = sigf(cp[i]);
        if (cl > PRE_TH) {
            int hw = i % HW;
            float s = cl * sigf(ct[hw]);
            uint32_t u = __float_as_uint(s);
            atomicAdd(&h[u >> 19], 1u);
        }
    }
    __syncthreads();
    uint32_t* gh = hist + n * L1B;
    for (int b = threadIdx.x; b < L1B; b += blockDim.x)
        if (h[b]) atomicAdd(&gh[b], h[b]);
}

// ---------------- scan 1: find level-1 boundary bucket ----------------
__global__ __launch_bounds__(256) void k_scan1(const uint32_t* __restrict__ hist,
                                               int* __restrict__ B1,
                                               int* __restrict__ need) {
    __shared__ uint32_t csum[256];
    const int n = blockIdx.x;
    const uint32_t* h = hist + n * L1B;
    const int t = threadIdx.x;
    uint32_t s = 0;
    for (int b = t * 16; b < t * 16 + 16; ++b) s += h[b];
    csum[t] = s;
    __syncthreads();
    if (t == 0) {
        long long acc = 0;
        int b1 = -1;
        for (int c = 255; c >= 0; --c) {
            if (acc + (long long)csum[c] >= TOPK) {
                for (int b = c * 16 + 15; b >= c * 16; --b) {
                    if (acc + (long long)h[b] >= TOPK) { b1 = b; break; }
                    acc += h[b];
                }
                break;
            }
            acc += csum[c];
        }
        if (b1 < 0) { B1[n] = 0; need[n] = 1 << 30; }  // fewer than TOPK candidates: take all
        else        { B1[n] = b1; need[n] = TOPK - (int)acc; }
    }
}

// ---------------- pass 2: level-2 histogram inside boundary bucket ----------------
__global__ __launch_bounds__(256) void k_hist2(const float* __restrict__ bcls,
                                               const float* __restrict__ bctr,
                                               const int* __restrict__ B1,
                                               uint32_t* __restrict__ hist2) {
    const int n = blockIdx.y;
    const int b1 = B1[n];
    const float* cp = bcls + (size_t)n * PER;
    const float* ct = bctr + n * HW;
    uint32_t* gh = hist2 + n * L2B;
    const int stride = gridDim.x * blockDim.x;
    for (int i = blockIdx.x * blockDim.x + threadIdx.x; i < PER; i += stride) {
        float cl = sigf(cp[i]);
        if (cl > PRE_TH) {
            int hw = i % HW;
            float s = cl * sigf(ct[hw]);
            uint32_t u = __float_as_uint(s);
            if ((int)(u >> 19) == b1)
                atomicAdd(&gh[(u >> 6) & (L2B - 1)], 1u);
        }
    }
}

// ---------------- scan 2: level-2 boundary sub-bucket ----------------
__global__ __launch_bounds__(256) void k_scan2(const uint32_t* __restrict__ hist2,
                                               const int* __restrict__ need,
                                               int* __restrict__ B2) {
    __shared__ uint32_t csum[256];
    const int n = blockIdx.x;
    const uint32_t* h = hist2 + n * L2B;
    const long long target = need[n];
    const int t = threadIdx.x;
    uint32_t s = 0;
    for (int b = t * 32; b < t * 32 + 32; ++b) s += h[b];
    csum[t] = s;
    __syncthreads();
    if (t == 0) {
        long long acc = 0;
        int b2 = 0;
        bool found = false;
        for (int c = 255; c >= 0 && !found; --c) {
            if (acc + (long long)csum[c] >= target) {
                for (int b = c * 32 + 31; b >= c * 32; --b) {
                    if (acc + (long long)h[b] >= target) { b2 = b; found = true; break; }
                    acc += h[b];
                }
            } else {
                acc += csum[c];
            }
        }
        B2[n] = b2;
    }
}

// ---------------- pass 3: compact selected candidates as sortable u64 keys ----------------
__global__ __launch_bounds__(256) void k_compact(const float* __restrict__ bcls,
                                                 const float* __restrict__ bctr,
                                                 const int* __restrict__ B1,
                                                 const int* __restrict__ B2,
                                                 int* __restrict__ cnt,
                                                 uint64_t* __restrict__ keys) {
    const int n = blockIdx.y;
    const int b1 = B1[n], b2 = B2[n];
    const float* cp = bcls + (size_t)n * PER;
    const float* ct = bctr + n * HW;
    uint64_t* kk = keys + (size_t)n * CAP;
    const int stride = gridDim.x * blockDim.x;
    for (int i = blockIdx.x * blockDim.x + threadIdx.x; i < PER; i += stride) {
        float cl = sigf(cp[i]);
        if (cl > PRE_TH) {
            int hw = i % HW;
            float s = cl * sigf(ct[hw]);
            uint32_t u = __float_as_uint(s);
            int e1 = (int)(u >> 19);
            int e2 = (int)((u >> 6) & (L2B - 1));
            if (e1 > b1 || (e1 == b1 && e2 >= b2)) {
                int pos = atomicAdd(&cnt[n], 1);
                if (pos < CAP) {
                    int c = i / HW;
                    uint32_t f = (uint32_t)(hw * NCLS + c);   // reference flat index hw*C+c
                    kk[pos] = ((uint64_t)u << 32) | (uint64_t)(0xFFFFFFFFu - f);
                }
            }
        }
    }
}

// ---------------- pass 4: per-image bitonic sort + decode + greedy NMS ----------------
__global__ __launch_bounds__(1024) void k_sortnms(const uint64_t* __restrict__ keys,
                                                  const int* __restrict__ cnt,
                                                  const float* __restrict__ loc,
                                                  const float* __restrict__ breg,
                                                  const int* __restrict__ imsz,
                                                  float* __restrict__ out) {
    __shared__ uint64_t sk[CAP];
    __shared__ float bx1[TOPK], by1[TOPK], bx2[TOPK], by2[TOPK], bsc[TOPK];
    __shared__ int bcl[TOPK];
    __shared__ unsigned char bval[TOPK];
    __shared__ int keepc;

    const int n = blockIdx.x;
    const int tid = threadIdx.x;
    int cn = cnt[n];
    if (cn > CAP) cn = CAP;

    const uint64_t* kk = keys + (size_t)n * CAP;
    for (int i = tid; i < CAP; i += blockDim.x)
        sk[i] = (i < cn) ? kk[i] : 0ULL;
    __syncthreads();

    // bitonic sort, descending
    for (int k = 2; k <= CAP; k <<= 1) {
        for (int j = k >> 1; j > 0; j >>= 1) {
            for (int i = tid; i < CAP; i += blockDim.x) {
                int ixj = i ^ j;
                if (ixj > i) {
                    uint64_t a = sk[i], b = sk[ixj];
                    bool desc = ((i & k) == 0);
                    if (desc ? (a < b) : (a > b)) { sk[i] = b; sk[ixj] = a; }
                }
            }
            __syncthreads();
        }
    }

    const int M = (cn < TOPK) ? cn : TOPK;

    // decode top-M candidates
    if (tid < M) {
        uint64_t key = sk[tid];
        uint32_t f = 0xFFFFFFFFu - (uint32_t)(key & 0xFFFFFFFFu);
        float sc = __uint_as_float((uint32_t)(key >> 32));
        int hw = (int)(f / NCLS);
        int c  = (int)(f % NCLS);
        float px = loc[2 * hw], py = loc[2 * hw + 1];
        const float* rg = breg + (size_t)n * 4 * HW;
        float l = rg[hw], t = rg[HW + hw], r = rg[2 * HW + hw], b = rg[3 * HW + hw];
        float wm = (float)imsz[n * 2 + 1] - 1.0f;
        float hm = (float)imsz[n * 2 + 0] - 1.0f;
        float x1 = fminf(fmaxf(px - l, 0.0f), wm);
        float y1 = fminf(fmaxf(py - t, 0.0f), hm);
        float x2 = fminf(fmaxf(px + r, 0.0f), wm);
        float y2 = fminf(fmaxf(py + b, 0.0f), hm);
        bx1[tid] = x1; by1[tid] = y1; bx2[tid] = x2; by2[tid] = y2;
        bsc[tid] = sc;
        bcl[tid] = c + 1;
        bval[tid] = (sc > 0.0f) ? 1 : 0;
    }

    // zero this image's output rows
    float* o = out + (size_t)n * KEEP * 6;
    for (int i = tid; i < KEEP * 6; i += blockDim.x) o[i] = 0.0f;
    if (tid == 0) keepc = 0;
    __syncthreads();

    // greedy NMS in sorted order == reference's argmax greedy
    for (int i = 0; i < M; ++i) {
        __syncthreads();
        int kc = keepc;                 // uniform
        if (kc >= KEEP) break;
        int vi = bval[i];               // uniform
        __syncthreads();                // reads done before writes below
        if (!vi) continue;
        if (tid == 0) {
            float* row = o + (size_t)kc * 6;
            row[0] = bx1[i]; row[1] = by1[i]; row[2] = bx2[i]; row[3] = by2[i];
            row[4] = bsc[i]; row[5] = (float)bcl[i];
            keepc = kc + 1;
        }
        float ax1 = bx1[i], ay1 = by1[i], ax2 = bx2[i], ay2 = by2[i];
        float aarea = fmaxf(ax2 - ax1, 0.0f) * fmaxf(ay2 - ay1, 0.0f);
        int ac = bcl[i];
        for (int j = i + 1 + tid; j < M; j += blockDim.x) {
            if (bval[j] && bcl[j] == ac) {
                float ix1 = fmaxf(ax1, bx1[j]), iy1 = fmaxf(ay1, by1[j]);
                float ix2 = fminf(ax2, bx2[j]), iy2 = fminf(ay2, by2[j]);
                float inter = fmaxf(ix2 - ix1, 0.0f) * fmaxf(iy2 - iy1, 0.0f);
                float barea = fmaxf(bx2[j] - bx1[j], 0.0f) * fmaxf(by2[j] - by1[j], 0.0f);
                float iou = inter / (aarea + barea - inter + 1e-9f);
                if (!(iou <= NMS_TH)) bval[j] = 0;
            }
        }
    }
}

// ---------------- launch ----------------
extern "C" void kernel_launch(void* const* d_in, const int* in_sizes, int n_in,
                              void* d_out, int out_size, void* d_ws, size_t ws_size,
                              hipStream_t stream) {
    const float* loc  = (const float*)d_in[0];   // [HW,2]
    const float* bcls = (const float*)d_in[1];   // [N,C,H,W]
    const float* breg = (const float*)d_in[2];   // [N,4,H,W]
    const float* bctr = (const float*)d_in[3];   // [N,1,H,W]
    const int*   imsz = (const int*)d_in[4];     // [N,2]
    float* out = (float*)d_out;                  // [N,100,6]

    uint8_t* ws = (uint8_t*)d_ws;
    uint32_t* h1  = (uint32_t*)(ws);                       // 8*4096*4   = 128KB
    uint32_t* h2  = (uint32_t*)(ws + 131072);              // 8*8192*4   = 256KB
    int*      meta = (int*)(ws + 393216);                  // B1[8] need[8] B2[8] cnt[8]
    int* B1 = meta, *need = meta + 8, *B2 = meta + 16, *cnt = meta + 24;
    uint64_t* keys = (uint64_t*)(ws + 394240);             // 8*4096*8   = 256KB

    hipMemsetAsync(d_ws, 0, 394240, stream);

    dim3 g(64, N_IMG);
    k_hist1  <<<g, 256, 0, stream>>>(bcls, bctr, h1);
    k_scan1  <<<N_IMG, 256, 0, stream>>>(h1, B1, need);
    k_hist2  <<<g, 256, 0, stream>>>(bcls, bctr, B1, h2);
    k_scan2  <<<N_IMG, 256, 0, stream>>>(h2, need, B2);
    k_compact<<<g, 256, 0, stream>>>(bcls, bctr, B1, B2, cnt, keys);
    k_sortnms<<<N_IMG, 1024, 0, stream>>>(keys, cnt, loc, breg, imsz, out);
}

// Round 3
// 355.469 us; speedup vs baseline: 1.0865x; 1.0865x over previous
//
#include <hip/hip_runtime.h>
#include <stdint.h>

#define N_IMG 8
#define NCLS  80
#define HW    10000
#define PER   (NCLS*HW)      /* 800000 per image */
#define L1B   4096           /* level-1 buckets: score bits 30:19 */
#define L2B   8192           /* level-2 buckets: score bits 18:6  */
#define TOPK  1000
#define CAP   2048           /* superset cap; cn ~= 1005 in practice */
#define KEEP  100
#define MROW  1024           /* padded row count for dec/mask buffers */
#define PRE_TH 0.05f
#define NMS_TH 0.6f
#define CLS_OFF 4096.0f

__device__ __forceinline__ float sigf(float x) {
    return 1.0f / (1.0f + expf(-x));
}

// ---------------- pass 1: level-1 histogram of candidate scores ----------------
__global__ __launch_bounds__(256) void k_hist1(const float* __restrict__ bcls,
                                               const float* __restrict__ bctr,
                                               uint32_t* __restrict__ hist) {
    __shared__ uint32_t h[L1B];
    const int n = blockIdx.y;
    for (int b = threadIdx.x; b < L1B; b += blockDim.x) h[b] = 0;
    __syncthreads();
    const float* cp = bcls + (size_t)n * PER;
    const float* ct = bctr + n * HW;
    const int stride = gridDim.x * blockDim.x;
    for (int i = blockIdx.x * blockDim.x + threadIdx.x; i < PER; i += stride) {
        float cl = sigf(cp[i]);
        if (cl > PRE_TH) {
            int hw = i % HW;
            float s = cl * sigf(ct[hw]);
            uint32_t u = __float_as_uint(s);
            atomicAdd(&h[u >> 19], 1u);
        }
    }
    __syncthreads();
    uint32_t* gh = hist + n * L1B;
    for (int b = threadIdx.x; b < L1B; b += blockDim.x)
        if (h[b]) atomicAdd(&gh[b], h[b]);
}

// ---------------- scan 1: find level-1 boundary bucket ----------------
__global__ __launch_bounds__(256) void k_scan1(const uint32_t* __restrict__ hist,
                                               int* __restrict__ B1,
                                               int* __restrict__ need) {
    __shared__ uint32_t csum[256];
    const int n = blockIdx.x;
    const uint32_t* h = hist + n * L1B;
    const int t = threadIdx.x;
    uint32_t s = 0;
    for (int b = t * 16; b < t * 16 + 16; ++b) s += h[b];
    csum[t] = s;
    __syncthreads();
    if (t == 0) {
        long long acc = 0;
        int b1 = -1;
        for (int c = 255; c >= 0; --c) {
            if (acc + (long long)csum[c] >= TOPK) {
                for (int b = c * 16 + 15; b >= c * 16; --b) {
                    if (acc + (long long)h[b] >= TOPK) { b1 = b; break; }
                    acc += h[b];
                }
                break;
            }
            acc += csum[c];
        }
        if (b1 < 0) { B1[n] = 0; need[n] = 1 << 30; }  // fewer than TOPK candidates: take all
        else        { B1[n] = b1; need[n] = TOPK - (int)acc; }
    }
}

// ---------------- pass 2: level-2 histogram inside boundary bucket ----------------
__global__ __launch_bounds__(256) void k_hist2(const float* __restrict__ bcls,
                                               const float* __restrict__ bctr,
                                               const int* __restrict__ B1,
                                               uint32_t* __restrict__ hist2) {
    const int n = blockIdx.y;
    const int b1 = B1[n];
    const float* cp = bcls + (size_t)n * PER;
    const float* ct = bctr + n * HW;
    uint32_t* gh = hist2 + n * L2B;
    const int stride = gridDim.x * blockDim.x;
    for (int i = blockIdx.x * blockDim.x + threadIdx.x; i < PER; i += stride) {
        float cl = sigf(cp[i]);
        if (cl > PRE_TH) {
            int hw = i % HW;
            float s = cl * sigf(ct[hw]);
            uint32_t u = __float_as_uint(s);
            if ((int)(u >> 19) == b1)
                atomicAdd(&gh[(u >> 6) & (L2B - 1)], 1u);
        }
    }
}

// ---------------- scan 2: level-2 boundary sub-bucket ----------------
__global__ __launch_bounds__(256) void k_scan2(const uint32_t* __restrict__ hist2,
                                               const int* __restrict__ need,
                                               int* __restrict__ B2) {
    __shared__ uint32_t csum[256];
    const int n = blockIdx.x;
    const uint32_t* h = hist2 + n * L2B;
    const long long target = need[n];
    const int t = threadIdx.x;
    uint32_t s = 0;
    for (int b = t * 32; b < t * 32 + 32; ++b) s += h[b];
    csum[t] = s;
    __syncthreads();
    if (t == 0) {
        long long acc = 0;
        int b2 = 0;
        bool found = false;
        for (int c = 255; c >= 0 && !found; --c) {
            if (acc + (long long)csum[c] >= target) {
                for (int b = c * 32 + 31; b >= c * 32; --b) {
                    if (acc + (long long)h[b] >= target) { b2 = b; found = true; break; }
                    acc += h[b];
                }
            } else {
                acc += csum[c];
            }
        }
        B2[n] = b2;
    }
}

// ---------------- pass 3: compact selected candidates as sortable u64 keys ----------------
__global__ __launch_bounds__(256) void k_compact(const float* __restrict__ bcls,
                                                 const float* __restrict__ bctr,
                                                 const int* __restrict__ B1,
                                                 const int* __restrict__ B2,
                                                 int* __restrict__ cnt,
                                                 uint64_t* __restrict__ keys) {
    const int n = blockIdx.y;
    const int b1 = B1[n], b2 = B2[n];
    const float* cp = bcls + (size_t)n * PER;
    const float* ct = bctr + n * HW;
    uint64_t* kk = keys + (size_t)n * CAP;
    const int stride = gridDim.x * blockDim.x;
    for (int i = blockIdx.x * blockDim.x + threadIdx.x; i < PER; i += stride) {
        float cl = sigf(cp[i]);
        if (cl > PRE_TH) {
            int hw = i % HW;
            float s = cl * sigf(ct[hw]);
            uint32_t u = __float_as_uint(s);
            int e1 = (int)(u >> 19);
            int e2 = (int)((u >> 6) & (L2B - 1));
            if (e1 > b1 || (e1 == b1 && e2 >= b2)) {
                int pos = atomicAdd(&cnt[n], 1);
                if (pos < CAP) {
                    int c = i / HW;
                    uint32_t f = (uint32_t)(hw * NCLS + c);   // reference flat index hw*C+c
                    kk[pos] = ((uint64_t)u << 32) | (uint64_t)(0xFFFFFFFFu - f);
                }
            }
        }
    }
}

// ---------------- pass 4: per-image bitonic sort + decode to SoA buffers ----------------
__global__ __launch_bounds__(1024) void k_sortdec(const uint64_t* __restrict__ keys,
                                                  const int* __restrict__ cnt,
                                                  const float* __restrict__ loc,
                                                  const float* __restrict__ breg,
                                                  const int* __restrict__ imsz,
                                                  float* __restrict__ dec) {
    __shared__ uint64_t sk[CAP];
    const int n = blockIdx.x;
    const int tid = threadIdx.x;
    int cn = cnt[n];
    if (cn > CAP) cn = CAP;

    const uint64_t* kk = keys + (size_t)n * CAP;
    for (int i = tid; i < CAP; i += blockDim.x)
        sk[i] = (i < cn) ? kk[i] : 0ULL;
    __syncthreads();

    // bitonic sort, descending (66 stages for CAP=2048)
    for (int k = 2; k <= CAP; k <<= 1) {
        for (int j = k >> 1; j > 0; j >>= 1) {
            for (int i = tid; i < CAP; i += blockDim.x) {
                int ixj = i ^ j;
                if (ixj > i) {
                    uint64_t a = sk[i], b = sk[ixj];
                    bool desc = ((i & k) == 0);
                    if (desc ? (a < b) : (a > b)) { sk[i] = b; sk[ixj] = a; }
                }
            }
            __syncthreads();
        }
    }

    const int M = (cn < TOPK) ? cn : TOPK;

    // decode top-M candidates into SoA dec[attr][n][MROW], attr = x1,y1,x2,y2,sc,cl
    if (tid < M) {
        uint64_t key = sk[tid];
        uint32_t f = 0xFFFFFFFFu - (uint32_t)(key & 0xFFFFFFFFu);
        float sc = __uint_as_float((uint32_t)(key >> 32));
        int hw = (int)(f / NCLS);
        int c  = (int)(f % NCLS);
        float px = loc[2 * hw], py = loc[2 * hw + 1];
        const float* rg = breg + (size_t)n * 4 * HW;
        float l = rg[hw], t = rg[HW + hw], r = rg[2 * HW + hw], b = rg[3 * HW + hw];
        float wm = (float)imsz[n * 2 + 1] - 1.0f;
        float hm = (float)imsz[n * 2 + 0] - 1.0f;
        float x1 = fminf(fmaxf(px - l, 0.0f), wm);
        float y1 = fminf(fmaxf(py - t, 0.0f), hm);
        float x2 = fminf(fmaxf(px + r, 0.0f), wm);
        float y2 = fminf(fmaxf(py + b, 0.0f), hm);
        const int base = n * MROW + tid;
        dec[0 * N_IMG * MROW + base] = x1;
        dec[1 * N_IMG * MROW + base] = y1;
        dec[2 * N_IMG * MROW + base] = x2;
        dec[3 * N_IMG * MROW + base] = y2;
        dec[4 * N_IMG * MROW + base] = sc;
        dec[5 * N_IMG * MROW + base] = (float)(c + 1);
    }
}

// ---------------- pass 5: parallel suppression-mask matrix ----------------
// mask[(n*MROW+i)*16 + jt] bit jj: !(IoU(offset box i, offset box j0+jj) <= 0.6)
// Offset coords (box + class*4096 in f32) replicate reference rounding exactly;
// cross-class pairs get IoU == 0 in both implementations.
__global__ __launch_bounds__(64) void k_mask(const float* __restrict__ dec,
                                             uint64_t* __restrict__ mask) {
    __shared__ float jx1[64], jy1[64], jx2[64], jy2[64];
    const int n  = blockIdx.z;
    const int jt = blockIdx.y;        // j-tile: 0..15
    const int t  = threadIdx.x;
    const int i  = blockIdx.x * 64 + t;
    const int j0 = jt * 64;

    // stage j-tile boxes (offset applied) into LDS
    {
        const int jb = n * MROW + j0 + t;
        float off = dec[5 * N_IMG * MROW + jb] * CLS_OFF;
        jx1[t] = dec[0 * N_IMG * MROW + jb] + off;
        jy1[t] = dec[1 * N_IMG * MROW + jb] + off;
        jx2[t] = dec[2 * N_IMG * MROW + jb] + off;
        jy2[t] = dec[3 * N_IMG * MROW + jb] + off;
    }
    __syncthreads();

    const int ib = n * MROW + i;
    float offi = dec[5 * N_IMG * MROW + ib] * CLS_OFF;
    float ax1 = dec[0 * N_IMG * MROW + ib] + offi;
    float ay1 = dec[1 * N_IMG * MROW + ib] + offi;
    float ax2 = dec[2 * N_IMG * MROW + ib] + offi;
    float ay2 = dec[3 * N_IMG * MROW + ib] + offi;
    float aarea = fmaxf(ax2 - ax1, 0.0f) * fmaxf(ay2 - ay1, 0.0f);

    uint64_t bits = 0;
    #pragma unroll 8
    for (int jj = 0; jj < 64; ++jj) {
        float ix1 = fmaxf(ax1, jx1[jj]), iy1 = fmaxf(ay1, jy1[jj]);
        float ix2 = fminf(ax2, jx2[jj]), iy2 = fminf(ay2, jy2[jj]);
        float inter = fmaxf(ix2 - ix1, 0.0f) * fmaxf(iy2 - iy1, 0.0f);
        float barea = fmaxf(jx2[jj] - jx1[jj], 0.0f) * fmaxf(jy2[jj] - jy1[jj], 0.0f);
        float iou = inter / (aarea + barea - inter + 1e-9f);
        bits |= ((uint64_t)(!(iou <= NMS_TH))) << jj;
    }
    mask[(size_t)(n * MROW + i) * 16 + jt] = bits;
}

// ---------------- pass 6: single-wave greedy scan per image ----------------
__global__ __launch_bounds__(64) void k_scan(const uint64_t* __restrict__ mask,
                                             const int* __restrict__ cnt,
                                             const float* __restrict__ dec,
                                             float* __restrict__ out) {
    const int n = blockIdx.x;
    const int lane = threadIdx.x;
    int cn = cnt[n];
    if (cn > CAP) cn = CAP;
    const int M = (cn < TOPK) ? cn : TOPK;

    const uint64_t* mk = mask + (size_t)n * MROW * 16;
    uint64_t rv = 0;      // lanes 0..15 hold suppression words 0..15
    int kc = 0;
    for (int i = 0; i < M; ++i) {
        uint64_t v = __shfl(rv, i >> 6, 64);          // broadcast word owning bit i
        if (!((v >> (i & 63)) & 1ull)) {              // uniform decision
            if (lane < 6)
                out[(size_t)(n * KEEP + kc) * 6 + lane] =
                    dec[lane * N_IMG * MROW + n * MROW + i];
            if (lane < 16)
                rv |= mk[(size_t)i * 16 + lane];
            if (++kc == KEEP) break;
        }
    }
}

// ---------------- launch ----------------
extern "C" void kernel_launch(void* const* d_in, const int* in_sizes, int n_in,
                              void* d_out, int out_size, void* d_ws, size_t ws_size,
                              hipStream_t stream) {
    const float* loc  = (const float*)d_in[0];   // [HW,2]
    const float* bcls = (const float*)d_in[1];   // [N,C,H,W]
    const float* breg = (const float*)d_in[2];   // [N,4,H,W]
    const float* bctr = (const float*)d_in[3];   // [N,1,H,W]
    const int*   imsz = (const int*)d_in[4];     // [N,2]
    float* out = (float*)d_out;                  // [N,100,6]

    uint8_t* ws = (uint8_t*)d_ws;
    uint32_t* h1   = (uint32_t*)(ws);                      // 8*4096*4  = 128KB
    uint32_t* h2   = (uint32_t*)(ws + 131072);             // 8*8192*4  = 256KB
    int*      meta = (int*)(ws + 393216);                  // B1[8] need[8] B2[8] cnt[8]
    int* B1 = meta, *need = meta + 8, *B2 = meta + 16, *cnt = meta + 24;
    uint64_t* keys = (uint64_t*)(ws + 393344);             // 8*2048*8  = 128KB  -> 524416
    float*    dec  = (float*)(ws + 524416);                // 6*8*1024*4 = 192KB -> 721024
    uint64_t* mask = (uint64_t*)(ws + 721024);             // 8*1024*16*8 = 1MB  -> 1769600

    hipMemsetAsync(d_ws, 0, 393344, stream);               // hists + meta
    hipMemsetAsync(d_out, 0, (size_t)out_size * sizeof(float), stream);

    dim3 g(64, N_IMG);
    k_hist1  <<<g, 256, 0, stream>>>(bcls, bctr, h1);
    k_scan1  <<<N_IMG, 256, 0, stream>>>(h1, B1, need);
    k_hist2  <<<g, 256, 0, stream>>>(bcls, bctr, B1, h2);
    k_scan2  <<<N_IMG, 256, 0, stream>>>(h2, need, B2);
    k_compact<<<g, 256, 0, stream>>>(bcls, bctr, B1, B2, cnt, keys);
    k_sortdec<<<N_IMG, 1024, 0, stream>>>(keys, cnt, loc, breg, imsz, dec);
    k_mask   <<<dim3(MROW / 64, 16, N_IMG), 64, 0, stream>>>(dec, mask);
    k_scan   <<<N_IMG, 64, 0, stream>>>(mask, cnt, dec, out);
}